// Round 4
// baseline (496.827 us; speedup 1.0000x reference)
//
#include <hip/hip_runtime.h>
#include <hip/hip_bf16.h>

typedef __attribute__((ext_vector_type(8))) short bf16x8;
typedef __attribute__((ext_vector_type(4))) float f32x4;
typedef __attribute__((ext_vector_type(2))) float f32x2;

static __device__ __forceinline__ float bf2f(unsigned short u){
  return __uint_as_float(((unsigned)u) << 16);
}
static __device__ __forceinline__ unsigned short f2bf(float f){
  unsigned u = __float_as_uint(f);
  u += 0x7FFFu + ((u >> 16) & 1u);
  return (unsigned short)(u >> 16);
}

#define MFMA16(acc, a, b) (acc) = __builtin_amdgcn_mfma_f32_16x16x32_bf16((a),(b),(acc),0,0,0)

#define NB   8
#define NVRT 2562
#define MP   2624      /* rows padded to 82*32 */
#define NSLAB 82       /* 32-row slabs */
#define NKT32 82       /* K tiles of 32 over MP (adj GEMM) */

// channel-last bf16 feature-map buffer bases (elements)
#define FT_B0 0ul
#define FT_B1 6422528ul
#define FT_B2 9633792ul
#define FT_B3 11239424ul
#define FT_TOT 12042240ul

// ---------------------------------------------------------------- unified transpose: 4 maps, [B,C,H,W]f32 -> [B,HW,C]bf16
__global__ void k_transpose_all(const float* __restrict__ c0, const float* __restrict__ c1,
                                const float* __restrict__ c2, const float* __restrict__ c3,
                                unsigned short* __restrict__ ftT)
{
  __shared__ float tile[32][33];
  int bx = blockIdx.x, b = blockIdx.y;
  int m, local;
  if (bx < 784)      { m = 0; local = bx; }
  else if (bx < 1184){ m = 1; local = bx - 784; }
  else if (bx < 1408){ m = 2; local = bx - 1184; }
  else               { m = 3; local = bx - 1408; }
  int HW  = (m==0)?3136:(m==1)?784:(m==2)?196:49;
  int C   = 256 << m;
  int nbx = (m==0)?98:(m==1)?25:(m==2)?7:2;
  size_t fb = (m==0)?FT_B0:(m==1)?FT_B1:(m==2)?FT_B2:FT_B3;
  const float* src = (m==0)?c0:(m==1)?c1:(m==2)?c2:c3;

  int hw0 = (local % nbx) * 32, c0i = (local / nbx) * 32;
  int tx = threadIdx.x, ty = threadIdx.y;
  const float* s = src + (size_t)b * C * HW;
#pragma unroll
  for (int i = 0; i < 4; i++){
    int c = c0i + ty + i*8, hw = hw0 + tx;
    tile[ty + i*8][tx] = (c < C && hw < HW) ? s[(size_t)c * HW + hw] : 0.f;
  }
  __syncthreads();
  unsigned short* d = ftT + fb + (size_t)b * HW * C;
#pragma unroll
  for (int i = 0; i < 4; i++){
    int hw = hw0 + ty + i*8, c = c0i + tx;
    if (hw < HW && c < C) d[(size_t)hw * C + c] = f2bf(tile[tx][ty + i*8]);
  }
}

// ---------------------------------------------------------------- unified weight pack: 7 weights -> [Kp/8][128][8] bf16
struct PWArgs {
  const float* src[7];
  unsigned short* dst[7];
  int ksrc[7], nsrc[7];
};
__global__ void k_packw_all(PWArgs a)
{
  const int cb[8] = {0,491520,528384,565248,585728,606208,626688,647168};
  int g = blockIdx.x * 256 + threadIdx.x;
#pragma unroll
  for (int s = 0; s < 7; s++){
    if (g >= cb[s] && g < cb[s+1]){
      int li = g - cb[s];
      int k = li >> 7, c = li & 127;
      int ks = a.ksrc[s], ns = a.nsrc[s];
      float v = (k < ks) ? a.src[s][(size_t)k * ns + c] : 0.f;
      a.dst[s][((size_t)(k >> 3) * 128 + c) * 8 + (k & 7)] = f2bf(v);
    }
  }
}

// ---------------------------------------------------------------- pack adjacency f32 -> bf16 per-lane FRAGMENT layout
// tile (b, slab32, kt32) = 1024 elems: [rf(2)][lane(64)][8]; lane: row16 = l&15, oct = l>>4
__global__ void k_adjpack(const float* __restrict__ adj, unsigned short* __restrict__ adjP)
{
  int kt = blockIdx.x, slab = blockIdx.y, b = blockIdx.z;
  int t = threadIdx.x;
  int r = t >> 3, h = t & 7;                 // row 0..31, half-octet 0..7 (4 k each)
  int grow = slab*32 + r, gk = kt*32 + h*4;
  float v0=0.f, v1=0.f, v2=0.f, v3=0.f;
  if (grow < NVRT){
    const float* ap = adj + ((size_t)b*NVRT + grow)*NVRT;
    if (gk + 4 <= NVRT){
      float4 f = *(const float4*)(ap + gk);
      v0=f.x; v1=f.y; v2=f.z; v3=f.w;
    } else {
      if (gk   < NVRT) v0 = ap[gk];
      if (gk+1 < NVRT) v1 = ap[gk+1];
      if (gk+2 < NVRT) v2 = ap[gk+2];
      if (gk+3 < NVRT) v3 = ap[gk+3];
    }
  }
  int lane = (r & 15) | ((h >> 1) << 4);
  size_t eoff = (((size_t)b*NSLAB + slab)*NKT32 + kt)*1024 + (r>>4)*512 + lane*8 + (h&1)*4;
  unsigned short* d = adjP + eoff;
  d[0]=f2bf(v0); d[1]=f2bf(v1); d[2]=f2bf(v2); d[3]=f2bf(v3);
}

// ---------------------------------------------------------------- meta(MP rows) + vf base cols + zero pads (wave-per-row)
__global__ void k_prep(const float* __restrict__ vfeat, const float* __restrict__ pos,
                       float* __restrict__ meta,
                       unsigned short* __restrict__ vf,
                       unsigned short* __restrict__ x1,
                       unsigned short* __restrict__ x2)
{
  int b = blockIdx.y;
  int row = blockIdx.x * 4 + (threadIdx.x >> 6);
  int lane = threadIdx.x & 63;
  size_t vfo = ((size_t)b * MP + row) * 288;
  size_t xo  = ((size_t)b * MP + row) * 160;
  if (row < NVRT){
    size_t src = (size_t)b * NVRT + row;
    if (lane < 4){
      int m = lane;
      float px = pos[src*3 + 0], py = pos[src*3 + 1];
      px = fminf(fmaxf(px, -1.f), 1.f);
      py = fminf(fmaxf(py, -1.f), 1.f);
      int W  = (m==0)?56:(m==1)?28:(m==2)?14:7;
      int C  = 256 << m;
      int HW = W * W;
      size_t Bm = (m==0)?FT_B0:(m==1)?FT_B1:(m==2)?FT_B2:FT_B3;
      float gx = (px + 1.f) * 0.5f * (float)(W - 1);
      float gy = (py + 1.f) * 0.5f * (float)(W - 1);
      int x0 = (int)floorf(gx), y0 = (int)floorf(gy);
      float wx = gx - (float)x0, wy = gy - (float)y0;
      int x1i = min(x0 + 1, W - 1), y1i = min(y0 + 1, W - 1);
      size_t base = Bm + (size_t)b * HW * C;
      float* mo = meta + ((size_t)b * MP + row) * 32 + m * 8;
      mo[0] = __int_as_float((int)(base + ((size_t)y0  * W + x0 ) * C));
      mo[1] = __int_as_float((int)(base + ((size_t)y0  * W + x1i) * C));
      mo[2] = __int_as_float((int)(base + ((size_t)y1i * W + x0 ) * C));
      mo[3] = __int_as_float((int)(base + ((size_t)y1i * W + x1i) * C));
      mo[4] = (1.f-wx)*(1.f-wy);
      mo[5] = wx*(1.f-wy);
      mo[6] = (1.f-wx)*wy;
      mo[7] = wx*wy;
    }
    for (int c = lane; c < 288; c += 64){
      if (c < 128)       vf[vfo + c] = f2bf(vfeat[src*128 + c]);
      else if (c < 131)  vf[vfo + c] = f2bf(pos[src*3 + (c - 128)]);
      else if (c >= 259) vf[vfo + c] = 0;
    }
    for (int c = lane; c < 160; c += 64){
      if (c < 3){
        unsigned short v = f2bf(pos[src*3 + c]);
        x1[xo + c] = v; x2[xo + c] = v;
      } else if (c >= 131){
        x1[xo + c] = 0; x2[xo + c] = 0;
      }
    }
  } else {
    if (lane < 32) meta[((size_t)b * MP + row) * 32 + lane] = 0.f;
    for (int c = lane; c < 288; c += 64) vf[vfo + c] = 0;
    for (int c = lane; c < 160; c += 64){ x1[xo + c] = 0; x2[xo + c] = 0; }
  }
}

// ---------------------------------------------------------------- fused vert_align + lin0: barrier-free K-loop, in-reg gather/blend
// grid 656 (b = bid&7, slab = bid>>3); 4 waves split K (120 ksteps of 32 -> 30 each)
__global__ __launch_bounds__(256) void k_lin0g(
    const unsigned short* __restrict__ ftT,
    const float* __restrict__ meta,
    const unsigned short* __restrict__ wp,
    const float* __restrict__ bias,
    unsigned short* __restrict__ vf)
{
  __shared__ f32x4 red[3][1024];
  int bid = blockIdx.x;
  int b = bid & 7, slab = bid >> 3;
  int t = threadIdx.x, w = t >> 6, lane = t & 63;
  int l15 = lane & 15, l4 = lane >> 4;

  f32x4 acc[2][8];
#pragma unroll
  for (int i = 0; i < 2; i++)
#pragma unroll
    for (int j = 0; j < 8; j++) acc[i][j] = (f32x4){0,0,0,0};

  const int mstart[4] = {0, 8, 24, 56};
  const int mend[4]   = {8, 24, 56, 120};
  const int mkoff[4]  = {0, 256, 768, 1792};
  int kbeg = w * 30, kend = kbeg + 30;

  int row0 = slab*32 + l15;       // rf=0 gather row
  int row1 = row0 + 16;           // rf=1

#pragma unroll
  for (int m = 0; m < 4; m++){
    int s = max(kbeg, mstart[m]), e = min(kend, mend[m]);
    if (s >= e) continue;
    int off[2][4]; float wt[2][4];
    const float* m0 = meta + ((size_t)b*MP + row0)*32 + m*8;
    const float* m1 = meta + ((size_t)b*MP + row1)*32 + m*8;
#pragma unroll
    for (int j = 0; j < 4; j++){
      off[0][j] = __float_as_int(m0[j]); wt[0][j] = m0[4+j];
      off[1][j] = __float_as_int(m1[j]); wt[1][j] = m1[4+j];
    }
    int koff = mkoff[m];
    for (int kt = s; kt < e; ++kt){
      int kk = kt*32 - koff + l4*8;
      bf16x8 afr[2];
#pragma unroll
      for (int rf = 0; rf < 2; rf++){
        bf16x8 g0 = *(const bf16x8*)(ftT + off[rf][0] + kk);
        bf16x8 g1 = *(const bf16x8*)(ftT + off[rf][1] + kk);
        bf16x8 g2 = *(const bf16x8*)(ftT + off[rf][2] + kk);
        bf16x8 g3 = *(const bf16x8*)(ftT + off[rf][3] + kk);
        float w0 = wt[rf][0], w1 = wt[rf][1], w2 = wt[rf][2], w3 = wt[rf][3];
#pragma unroll
        for (int e8 = 0; e8 < 8; e8++){
          float f = w0*bf2f((unsigned short)g0[e8]) + w1*bf2f((unsigned short)g1[e8])
                  + w2*bf2f((unsigned short)g2[e8]) + w3*bf2f((unsigned short)g3[e8]);
          afr[rf][e8] = (short)f2bf(f);
        }
      }
      const unsigned short* bp = wp + ((size_t)(kt*4 + l4)*128 + l15)*8;
#pragma unroll
      for (int cf = 0; cf < 8; cf++){
        bf16x8 bb = *(const bf16x8*)(bp + cf*128);
        MFMA16(acc[0][cf], afr[0], bb);
        MFMA16(acc[1][cf], afr[1], bb);
      }
    }
  }

  if (w){
#pragma unroll
    for (int rf = 0; rf < 2; rf++)
#pragma unroll
      for (int cf = 0; cf < 8; cf++)
        red[w-1][(rf*8+cf)*64 + lane] = acc[rf][cf];
  }
  __syncthreads();
  if (!w){
#pragma unroll
    for (int rf = 0; rf < 2; rf++)
#pragma unroll
      for (int cf = 0; cf < 8; cf++){
        int i = (rf*8+cf)*64 + lane;
        f32x4 s = acc[rf][cf] + red[0][i] + red[1][i] + red[2][i];
        int col = cf*16 + l15;
        float bv = bias[col];
#pragma unroll
        for (int r = 0; r < 4; r++){
          int row = slab*32 + rf*16 + l4*4 + r;
          if (row < NVRT)
            vf[((size_t)b*MP + row)*288 + 131 + col] = f2bf(s[r] + bv);
        }
      }
  }
}

// ---------------------------------------------------------------- y0 = x@w0 (f32), y1p = pack(x@w1) (bf16); barrier-free
template<int KX>
__global__ __launch_bounds__(256) void k_xw2(
    const unsigned short* __restrict__ x,
    const unsigned short* __restrict__ wp0,
    const unsigned short* __restrict__ wp1,
    float* __restrict__ y0,
    unsigned short* __restrict__ y1p)
{
  int bid = blockIdx.x;
  int b = bid & 7, rb = (bid >> 3) * 32;
  int t = threadIdx.x, wave = t >> 6, lane = t & 63;
  int rf = wave & 1, ch = wave >> 1;
  int l15 = lane & 15, l4 = lane >> 4;
  f32x4 a0[4], a1[4];
#pragma unroll
  for (int c = 0; c < 4; c++){ a0[c] = (f32x4){0,0,0,0}; a1[c] = (f32x4){0,0,0,0}; }
  int row = rb + rf*16 + l15;
  const unsigned short* xp = x + ((size_t)b * MP + row) * KX + l4 * 8;
#pragma unroll
  for (int kb = 0; kb < KX; kb += 32){
    bf16x8 a = *(const bf16x8*)(xp + kb);
    size_t bo = ((size_t)((kb>>3) + l4) * 128 + ch*64 + l15) * 8;
#pragma unroll
    for (int c = 0; c < 4; c++){
      bf16x8 b0 = *(const bf16x8*)(wp0 + bo + c*128);
      MFMA16(a0[c], a, b0);
      bf16x8 b1 = *(const bf16x8*)(wp1 + bo + c*128);
      MFMA16(a1[c], a, b1);
    }
  }
#pragma unroll
  for (int c = 0; c < 4; c++){
    int col = ch*64 + c*16 + l15;
#pragma unroll
    for (int r = 0; r < 4; r++){
      int orow = rb + rf*16 + l4*4 + r;
      y0[((size_t)b * MP + orow) * 128 + col] = a0[c][r];
      y1p[(((size_t)b * (MP/8) + (orow>>3)) * 128 + col) * 8 + (orow & 7)] = f2bf(a1[c][r]);
    }
  }
}

// ---------------------------------------------------------------- adj GEMM: barrier-free K-loop from fragment-packed adjP
// grid 656 (b = bid&7, slab = bid>>3); 4 waves split K (82 ksteps -> 21/21/21/19)
// fused epilogue: h = relu(y0 + adj@y1); EPI=0 -> xnext bf16; EPI=1 -> outf f32
template<int EPI>
__global__ __launch_bounds__(256) void k_adjs(
    const unsigned short* __restrict__ adjP,
    const unsigned short* __restrict__ y1p,
    const float* __restrict__ y0,
    unsigned short* __restrict__ xnext,
    float* __restrict__ outf)
{
  __shared__ f32x4 red[3][1024];
  int bid = blockIdx.x;
  int b = bid & 7, slab = bid >> 3;
  int t = threadIdx.x, w = t >> 6, lane = t & 63;
  int l15 = lane & 15, l4 = lane >> 4;
  const unsigned short* A = adjP + (((size_t)b*NSLAB + slab)*NKT32)*1024;
  const unsigned short* Bp = y1p + (size_t)b * (MP/8) * 128 * 8;

  f32x4 acc[2][8];
#pragma unroll
  for (int i = 0; i < 2; i++)
#pragma unroll
    for (int j = 0; j < 8; j++) acc[i][j] = (f32x4){0,0,0,0};

  int k0 = w * 21, k1 = min(NKT32, k0 + 21);
#pragma unroll 2
  for (int kt = k0; kt < k1; ++kt){
    bf16x8 af0 = *(const bf16x8*)(A + (size_t)kt*1024 + lane*8);
    bf16x8 af1 = *(const bf16x8*)(A + (size_t)kt*1024 + 512 + lane*8);
    const unsigned short* bp = Bp + ((size_t)(kt*4 + l4)*128 + l15)*8;
#pragma unroll
    for (int cf = 0; cf < 8; cf++){
      bf16x8 bb = *(const bf16x8*)(bp + cf*128);
      MFMA16(acc[0][cf], af0, bb);
      MFMA16(acc[1][cf], af1, bb);
    }
  }

  if (w){
#pragma unroll
    for (int rf = 0; rf < 2; rf++)
#pragma unroll
      for (int cf = 0; cf < 8; cf++)
        red[w-1][(rf*8+cf)*64 + lane] = acc[rf][cf];
  }
  __syncthreads();
  if (!w){
#pragma unroll
    for (int rf = 0; rf < 2; rf++)
#pragma unroll
      for (int cf = 0; cf < 8; cf++){
        int i = (rf*8+cf)*64 + lane;
        f32x4 s = acc[rf][cf] + red[0][i] + red[1][i] + red[2][i];
        int col = cf*16 + l15;
#pragma unroll
        for (int r = 0; r < 4; r++){
          int row = slab*32 + rf*16 + l4*4 + r;
          if (row < NVRT){
            float v = fmaxf(y0[((size_t)b*MP + row)*128 + col] + s[r], 0.f);
            if (EPI == 0) xnext[((size_t)b*MP + row)*160 + 3 + col] = f2bf(v);
            else          outf[((size_t)b*NVRT + row)*128 + col] = v;
          }
        }
      }
  }
}

// ---------------------------------------------------------------- position head: new_pos = pos + tanh(feat @ w_lin1 + b_lin1)
__global__ void k_head(const float* __restrict__ feat, const float* __restrict__ pos,
                       const float* __restrict__ wl1, const float* __restrict__ bl1,
                       float* __restrict__ opos)
{
  int grow = blockIdx.x * 4 + (threadIdx.x >> 6);
  int lane = threadIdx.x & 63;
  int b = grow / NVRT, row = grow - b * NVRT;
  int c0 = lane * 2;
  f32x2 v = *(const f32x2*)(feat + ((size_t)b * NVRT + row) * 128 + c0);
  float p[3];
#pragma unroll
  for (int j = 0; j < 3; j++){
    p[j] = v[0] * wl1[c0*3 + j] + v[1] * wl1[c0*3 + 3 + j];
#pragma unroll
    for (int off = 1; off < 64; off <<= 1)
      p[j] += __shfl_xor(p[j], off);
  }
  if (lane == 0){
    size_t po = ((size_t)b * NVRT + row) * 3;
#pragma unroll
    for (int j = 0; j < 3; j++)
      opos[po + j] = pos[po + j] + tanhf(p[j] + bl1[j]);
  }
}

// ================================================================ host
extern "C" void kernel_launch(void* const* d_in, const int* in_sizes, int n_in,
                              void* d_out, int out_size, void* d_ws, size_t ws_size,
                              hipStream_t stream)
{
  const float* conv[4] = {(const float*)d_in[0], (const float*)d_in[1],
                          (const float*)d_in[2], (const float*)d_in[3]};
  const float* adj   = (const float*)d_in[4];
  const float* pos   = (const float*)d_in[5];
  const float* vfeat = (const float*)d_in[6];
  const float* wlin0 = (const float*)d_in[7];
  const float* blin0 = (const float*)d_in[8];
  const float* gw[6] = {(const float*)d_in[9],  (const float*)d_in[10],
                        (const float*)d_in[11], (const float*)d_in[12],
                        (const float*)d_in[13], (const float*)d_in[14]};
  const float* wlin1 = (const float*)d_in[15];
  const float* blin1 = (const float*)d_in[16];

  char* ws = (char*)d_ws;
  size_t off = 0;
  auto take = [&](size_t bytes)->char* {
    char* p = ws + off;
    off += (bytes + 255) & ~(size_t)255;
    return p;
  };
  unsigned short* ftT  = (unsigned short*)take(FT_TOT * 2);
  float*          meta = (float*)take((size_t)NB*MP*32*4);
  unsigned short* adjP = (unsigned short*)take((size_t)NB*NSLAB*NKT32*2048);
  unsigned short* wl0p = (unsigned short*)take((size_t)3840*128*2);
  unsigned short* w0p0 = (unsigned short*)take((size_t)288*128*2);
  unsigned short* w1p0 = (unsigned short*)take((size_t)288*128*2);
  unsigned short* w0p1 = (unsigned short*)take((size_t)160*128*2);
  unsigned short* w1p1 = (unsigned short*)take((size_t)160*128*2);
  unsigned short* w0p2 = (unsigned short*)take((size_t)160*128*2);
  unsigned short* w1p2 = (unsigned short*)take((size_t)160*128*2);
  unsigned short* vf   = (unsigned short*)take((size_t)NB*MP*288*2);
  unsigned short* x1   = (unsigned short*)take((size_t)NB*MP*160*2);
  unsigned short* x2   = (unsigned short*)take((size_t)NB*MP*160*2);
  float*          y0   = (float*)take((size_t)NB*MP*128*4);
  unsigned short* y1p  = (unsigned short*)take((size_t)NB*MP*128*2);

  float* out_pos  = (float*)d_out;
  float* out_feat = out_pos + (size_t)NB*NVRT*3;

  // 1. transposes (one dispatch)
  k_transpose_all<<<dim3(1536, NB), dim3(32, 8), 0, stream>>>(conv[0], conv[1], conv[2], conv[3], ftT);
  // 2. weight packing (one dispatch)
  PWArgs pw;
  pw.src[0]=wlin0; pw.dst[0]=wl0p; pw.ksrc[0]=3840; pw.nsrc[0]=128;
  pw.src[1]=gw[0]; pw.dst[1]=w0p0; pw.ksrc[1]=259;  pw.nsrc[1]=131;
  pw.src[2]=gw[1]; pw.dst[2]=w1p0; pw.ksrc[2]=259;  pw.nsrc[2]=131;
  pw.src[3]=gw[2]; pw.dst[3]=w0p1; pw.ksrc[3]=131;  pw.nsrc[3]=128;
  pw.src[4]=gw[3]; pw.dst[4]=w1p1; pw.ksrc[4]=131;  pw.nsrc[4]=128;
  pw.src[5]=gw[4]; pw.dst[5]=w0p2; pw.ksrc[5]=131;  pw.nsrc[5]=128;
  pw.src[6]=gw[5]; pw.dst[6]=w1p2; pw.ksrc[6]=131;  pw.nsrc[6]=128;
  k_packw_all<<<2528, 256, 0, stream>>>(pw);
  // 3. meta + vf base + pads (one dispatch)
  k_prep<<<dim3(MP/4, NB), 256, 0, stream>>>(vfeat, pos, meta, vf, x1, x2);
  // 4. fused vert_align + lin0 (barrier-free, in-block K-split)
  k_lin0g<<<NSLAB*NB, 256, 0, stream>>>(ftT, meta, wl0p, blin0, vf);
  // 5. pack adjacency to fragment layout (after lin0g so ftT stays cache-warm for the gathers)
  k_adjpack<<<dim3(NKT32, NSLAB, NB), 256, 0, stream>>>(adj, adjP);
  // 6-8. three graph convs
  k_xw2<288><<<NSLAB*NB, 256, 0, stream>>>(vf, w0p0, w1p0, y0, y1p);
  k_adjs<0><<<NSLAB*NB, 256, 0, stream>>>(adjP, y1p, y0, x1, nullptr);
  k_xw2<160><<<NSLAB*NB, 256, 0, stream>>>(x1, w0p1, w1p1, y0, y1p);
  k_adjs<0><<<NSLAB*NB, 256, 0, stream>>>(adjP, y1p, y0, x2, nullptr);
  k_xw2<160><<<NSLAB*NB, 256, 0, stream>>>(x2, w0p2, w1p2, y0, y1p);
  k_adjs<1><<<NSLAB*NB, 256, 0, stream>>>(adjP, y1p, y0, nullptr, out_feat);
  // 9. position head
  k_head<<<NB*NVRT/4, 256, 0, stream>>>(out_feat, pos, wlin1, blin1, out_pos);
  (void)in_sizes; (void)n_in; (void)out_size; (void)ws_size;
}

// Round 5
// 320.558 us; speedup vs baseline: 1.5499x; 1.5499x over previous
//
#include <hip/hip_runtime.h>
#include <hip/hip_bf16.h>

typedef __attribute__((ext_vector_type(8))) short bf16x8;
typedef __attribute__((ext_vector_type(4))) float f32x4;
typedef __attribute__((ext_vector_type(2))) float f32x2;

static __device__ __forceinline__ float bf2f(unsigned short u){
  return __uint_as_float(((unsigned)u) << 16);
}
static __device__ __forceinline__ float bflo(unsigned v){ return __uint_as_float(v << 16); }
static __device__ __forceinline__ float bfhi(unsigned v){ return __uint_as_float(v & 0xffff0000u); }
static __device__ __forceinline__ unsigned short f2bf(float f){
  unsigned u = __float_as_uint(f);
  u += 0x7FFFu + ((u >> 16) & 1u);
  return (unsigned short)(u >> 16);
}
static __device__ __forceinline__ void gload_lds16(const void* g, void* l){
  __builtin_amdgcn_global_load_lds((const __attribute__((address_space(1))) unsigned int*)g,
                                   (__attribute__((address_space(3))) unsigned int*)l, 16, 0, 0);
}

#define MFMA16(acc, a, b) (acc) = __builtin_amdgcn_mfma_f32_16x16x32_bf16((a),(b),(acc),0,0,0)

#define NB   8
#define NVRT 2562
#define MP   2624      /* rows padded to 82*32 */
#define NRB2 82        /* 32-row blocks */
#define NKT  41        /* K tiles of 64 over MP */

// channel-last bf16 feature-map buffer bases (elements)
#define FT_B0 0ul
#define FT_B1 6422528ul
#define FT_B2 9633792ul
#define FT_B3 11239424ul
#define FT_TOT 12042240ul

// pixel-projection buffer bases (elements), layout [B*HW][128] bf16 per map
#define G_B0 0ul
#define G_B1 3211264ul
#define G_B2 4014080ul
#define G_B3 4214784ul
#define G_TOT 4264960ul

// ---------------------------------------------------------------- unified transpose: 4 maps, [B,C,H,W]f32 -> [B,HW,C]bf16
__global__ void k_transpose_all(const float* __restrict__ c0, const float* __restrict__ c1,
                                const float* __restrict__ c2, const float* __restrict__ c3,
                                unsigned short* __restrict__ ftT)
{
  __shared__ float tile[32][33];
  int bx = blockIdx.x, b = blockIdx.y;
  int m, local;
  if (bx < 784)      { m = 0; local = bx; }
  else if (bx < 1184){ m = 1; local = bx - 784; }
  else if (bx < 1408){ m = 2; local = bx - 1184; }
  else               { m = 3; local = bx - 1408; }
  int HW  = (m==0)?3136:(m==1)?784:(m==2)?196:49;
  int C   = 256 << m;
  int nbx = (m==0)?98:(m==1)?25:(m==2)?7:2;
  size_t fb = (m==0)?FT_B0:(m==1)?FT_B1:(m==2)?FT_B2:FT_B3;
  const float* src = (m==0)?c0:(m==1)?c1:(m==2)?c2:c3;

  int hw0 = (local % nbx) * 32, c0i = (local / nbx) * 32;
  int tx = threadIdx.x, ty = threadIdx.y;
  const float* s = src + (size_t)b * C * HW;
#pragma unroll
  for (int i = 0; i < 4; i++){
    int c = c0i + ty + i*8, hw = hw0 + tx;
    tile[ty + i*8][tx] = (c < C && hw < HW) ? s[(size_t)c * HW + hw] : 0.f;
  }
  __syncthreads();
  unsigned short* d = ftT + fb + (size_t)b * HW * C;
#pragma unroll
  for (int i = 0; i < 4; i++){
    int hw = hw0 + ty + i*8, c = c0i + tx;
    if (hw < HW && c < C) d[(size_t)hw * C + c] = f2bf(tile[tx][ty + i*8]);
  }
}

// ---------------------------------------------------------------- unified weight pack: 7 weights -> [Kp/8][128][8] bf16
struct PWArgs {
  const float* src[7];
  unsigned short* dst[7];
  int ksrc[7], nsrc[7];
};
__global__ void k_packw_all(PWArgs a)
{
  const int cb[8] = {0,491520,528384,565248,585728,606208,626688,647168};
  int g = blockIdx.x * 256 + threadIdx.x;
#pragma unroll
  for (int s = 0; s < 7; s++){
    if (g >= cb[s] && g < cb[s+1]){
      int li = g - cb[s];
      int k = li >> 7, c = li & 127;
      int ks = a.ksrc[s], ns = a.nsrc[s];
      float v = (k < ks) ? a.src[s][(size_t)k * ns + c] : 0.f;
      a.dst[s][((size_t)(k >> 3) * 128 + c) * 8 + (k & 7)] = f2bf(v);
    }
  }
}

// ---------------------------------------------------------------- pixel projection: G_m = ftT_m @ W_m  (linearity trick)
// one block = 32 pixel rows x 128 cols; 4 waves (rf = row-half, ch = col-half)
__global__ __launch_bounds__(256) void k_gproj(
    const unsigned short* __restrict__ ftT,
    const unsigned short* __restrict__ wp,
    unsigned short* __restrict__ G)
{
  int bx = blockIdx.x;
  int m, tile;
  if (bx < 784)      { m = 0; tile = bx; }
  else if (bx < 980) { m = 1; tile = bx - 784; }
  else if (bx < 1029){ m = 2; tile = bx - 980; }
  else               { m = 3; tile = bx - 1029; }
  int C    = 256 << m;
  int rows = 8 * ((m==0)?3136:(m==1)?784:(m==2)?196:49);
  size_t fb = (m==0)?FT_B0:(m==1)?FT_B1:(m==2)?FT_B2:FT_B3;
  size_t gb = (m==0)?G_B0:(m==1)?G_B1:(m==2)?G_B2:G_B3;
  int ko8 = ((m==0)?0:(m==1)?256:(m==2)?768:1792) >> 3;

  int t = threadIdx.x, wave = t >> 6, lane = t & 63;
  int rf = wave & 1, ch = wave >> 1;
  int l15 = lane & 15, l4 = lane >> 4;
  int row = tile*32 + rf*16 + l15;
  int arow = (row < rows) ? row : 0;
  const unsigned short* xp = ftT + fb + (size_t)arow * C + l4 * 8;

  f32x4 acc[4];
#pragma unroll
  for (int c = 0; c < 4; c++) acc[c] = (f32x4){0,0,0,0};

  for (int kb = 0; kb < C; kb += 32){
    bf16x8 a = *(const bf16x8*)(xp + kb);
    size_t bo = ((size_t)(ko8 + (kb>>3) + l4) * 128 + ch*64 + l15) * 8;
#pragma unroll
    for (int c = 0; c < 4; c++){
      bf16x8 bb = *(const bf16x8*)(wp + bo + c*128);
      MFMA16(acc[c], a, bb);
    }
  }
#pragma unroll
  for (int c = 0; c < 4; c++){
    int col = ch*64 + c*16 + l15;
#pragma unroll
    for (int r = 0; r < 4; r++){
      int orow = tile*32 + rf*16 + l4*4 + r;
      if (orow < rows) G[gb + (size_t)orow*128 + col] = f2bf(acc[c][r]);
    }
  }
}

// ---------------------------------------------------------------- prep: gather-blend projected from G + vf base + x1/x2 pads
// wave-per-row
__global__ void k_prep2(const float* __restrict__ vfeat, const float* __restrict__ pos,
                        const unsigned short* __restrict__ G,
                        const float* __restrict__ bias,
                        unsigned short* __restrict__ vf,
                        unsigned short* __restrict__ x1,
                        unsigned short* __restrict__ x2)
{
  int b = blockIdx.y;
  int row = blockIdx.x * 4 + (threadIdx.x >> 6);
  int lane = threadIdx.x & 63;
  size_t vfo = ((size_t)b * MP + row) * 288;
  size_t xo  = ((size_t)b * MP + row) * 160;
  if (row < NVRT){
    size_t src = (size_t)b * NVRT + row;
    float px = fminf(fmaxf(pos[src*3 + 0], -1.f), 1.f);
    float py = fminf(fmaxf(pos[src*3 + 1], -1.f), 1.f);
    int c0 = lane * 2;
    float s0 = bias[c0], s1 = bias[c0 + 1];
#pragma unroll
    for (int m = 0; m < 4; m++){
      int W = 56 >> m;
      int HW = W * W;
      size_t gb = (m==0)?G_B0:(m==1)?G_B1:(m==2)?G_B2:G_B3;
      float gx = (px + 1.f) * 0.5f * (float)(W - 1);
      float gy = (py + 1.f) * 0.5f * (float)(W - 1);
      int x0 = (int)floorf(gx), y0 = (int)floorf(gy);
      float wx = gx - (float)x0, wy = gy - (float)y0;
      int x1i = min(x0 + 1, W - 1), y1i = min(y0 + 1, W - 1);
      const unsigned short* g = G + gb + (size_t)b * HW * 128;
      unsigned v00 = *(const unsigned*)(g + ((size_t)(y0 *W + x0 ))*128 + c0);
      unsigned v01 = *(const unsigned*)(g + ((size_t)(y0 *W + x1i))*128 + c0);
      unsigned v10 = *(const unsigned*)(g + ((size_t)(y1i*W + x0 ))*128 + c0);
      unsigned v11 = *(const unsigned*)(g + ((size_t)(y1i*W + x1i))*128 + c0);
      float w00 = (1.f-wx)*(1.f-wy), w01 = wx*(1.f-wy);
      float w10 = (1.f-wx)*wy,       w11 = wx*wy;
      s0 += w00*bflo(v00) + w01*bflo(v01) + w10*bflo(v10) + w11*bflo(v11);
      s1 += w00*bfhi(v00) + w01*bfhi(v01) + w10*bfhi(v10) + w11*bfhi(v11);
    }
    vf[vfo + 131 + c0]     = f2bf(s0);
    vf[vfo + 131 + c0 + 1] = f2bf(s1);
    float2 fv = *(const float2*)(vfeat + src*128 + c0);
    vf[vfo + c0]     = f2bf(fv.x);
    vf[vfo + c0 + 1] = f2bf(fv.y);
    if (lane < 3){
      unsigned short v = f2bf(pos[src*3 + lane]);
      vf[vfo + 128 + lane] = v;
      x1[xo + lane] = v;
      x2[xo + lane] = v;
    }
    if (lane >= 32 && lane < 61) vf[vfo + 259 + (lane - 32)] = 0;
    if (lane < 29){ x1[xo + 131 + lane] = 0; x2[xo + 131 + lane] = 0; }
  } else {
    for (int c = lane; c < 288; c += 64) vf[vfo + c] = 0;
    for (int c = lane; c < 160; c += 64){ x1[xo + c] = 0; x2[xo + c] = 0; }
  }
}

// ---------------------------------------------------------------- pack adjacency f32 -> bf16 MFMA tiles with baked XOR swizzle
// layout: [B][82 rowblk][41 ktile] of 4KB tiles; tile byte = row*128 + ((k8*16) ^ ((row&7)<<4))
__global__ void k_adjpack(const float* __restrict__ adj, unsigned short* __restrict__ adjP)
{
  int kt = blockIdx.x, rb = blockIdx.y, b = blockIdx.z;
  int t = threadIdx.x, row = t >> 3, k8 = t & 7;
  int grow = rb*32 + row, gk = kt*64 + k8*8;
  unsigned short o[8];
  if (grow < NVRT && gk + 8 <= NVRT){
    const float2* p = (const float2*)(adj + ((size_t)b*NVRT + grow)*NVRT + gk);
    float2 f0 = p[0], f1 = p[1], f2 = p[2], f3 = p[3];
    o[0]=f2bf(f0.x); o[1]=f2bf(f0.y); o[2]=f2bf(f1.x); o[3]=f2bf(f1.y);
    o[4]=f2bf(f2.x); o[5]=f2bf(f2.y); o[6]=f2bf(f3.x); o[7]=f2bf(f3.y);
  } else if (grow < NVRT){
    const float* ap = adj + ((size_t)b*NVRT + grow)*NVRT;
#pragma unroll
    for (int e = 0; e < 8; e++){ int k = gk + e; o[e] = (k < NVRT) ? f2bf(ap[k]) : 0; }
  } else {
#pragma unroll
    for (int e = 0; e < 8; e++) o[e] = 0;
  }
  bf16x8 h;
#pragma unroll
  for (int e = 0; e < 8; e++) h[e] = (short)o[e];
  char* tb = (char*)(adjP + (((size_t)b*NRB2 + rb)*NKT + kt) * 2048);
  *(bf16x8*)(tb + row*128 + ((k8*16) ^ ((row&7)<<4))) = h;
}

// ---------------------------------------------------------------- y0 = x@w0 (f32), y1p = pack(x@w1) (bf16)
template<int KX>
__global__ __launch_bounds__(256) void k_xw2(
    const unsigned short* __restrict__ x,
    const unsigned short* __restrict__ wp0,
    const unsigned short* __restrict__ wp1,
    float* __restrict__ y0,
    unsigned short* __restrict__ y1p)
{
  int b = blockIdx.y, rb = blockIdx.x * 32;
  int t = threadIdx.x, wave = t >> 6, lane = t & 63;
  int rf = wave & 1, ch = wave >> 1;
  int l15 = lane & 15, l4 = lane >> 4;
  f32x4 a0[4], a1[4];
#pragma unroll
  for (int c = 0; c < 4; c++){ a0[c] = (f32x4){0,0,0,0}; a1[c] = (f32x4){0,0,0,0}; }
  int row = rb + rf*16 + l15;
  const unsigned short* xp = x + ((size_t)b * MP + row) * KX + l4 * 8;
#pragma unroll
  for (int kb = 0; kb < KX; kb += 32){
    bf16x8 a = *(const bf16x8*)(xp + kb);
    size_t bo = ((size_t)((kb>>3) + l4) * 128 + ch*64 + l15) * 8;
#pragma unroll
    for (int c = 0; c < 4; c++){
      bf16x8 b0 = *(const bf16x8*)(wp0 + bo + c*128);
      MFMA16(a0[c], a, b0);
      bf16x8 b1 = *(const bf16x8*)(wp1 + bo + c*128);
      MFMA16(a1[c], a, b1);
    }
  }
#pragma unroll
  for (int c = 0; c < 4; c++){
    int col = ch*64 + c*16 + l15;
#pragma unroll
    for (int r = 0; r < 4; r++){
      int orow = rb + rf*16 + l4*4 + r;
      y0[((size_t)b * MP + orow) * 128 + col] = a0[c][r];
      y1p[(((size_t)b * (MP/8) + (orow>>3)) * 128 + col) * 8 + (orow & 7)] = f2bf(a1[c][r]);
    }
  }
}

// ---------------------------------------------------------------- h = relu(y0 + adj@y1) from PACKED bf16 adjacency
// 32-row tiles, global_load_lds staging, dbuf, 2-phase pipeline (round-2 proven)
template<int EPI>
__global__ __launch_bounds__(256) void k_adj2(
    const unsigned short* __restrict__ adjP,
    const unsigned short* __restrict__ y1p,
    const float* __restrict__ y0,
    unsigned short* __restrict__ xnext,
    float* __restrict__ outf)
{
  __shared__ __align__(16) unsigned short abuf[2][2048];
  int b = blockIdx.y, rb = blockIdx.x;
  int t = threadIdx.x, wave = t >> 6, lane = t & 63;
  int l15 = lane & 15, l4 = lane >> 4;
  const unsigned short* tbase = adjP + (((size_t)b*NRB2 + rb)*NKT) * 2048;
  const unsigned short* y1b = y1p + (size_t)b * (MP/8) * 128 * 8;

  f32x4 acc[2][2];
#pragma unroll
  for (int i = 0; i < 2; i++)
#pragma unroll
    for (int j = 0; j < 2; j++) acc[i][j] = (f32x4){0,0,0,0};

  auto stage = [&](int kt, int bufi){
    gload_lds16(tbase + (size_t)kt*2048 + t*8, &abuf[bufi][wave*512]);
  };

  stage(0, 0);
  __syncthreads();

  for (int kt = 0; kt < NKT; ++kt){
    int cur = kt & 1;
    if (kt < NKT-1) stage(kt+1, cur ^ 1);
    bf16x8 bfr[2][2];
#pragma unroll
    for (int cf = 0; cf < 2; cf++)
#pragma unroll
      for (int ks = 0; ks < 2; ks++)
        bfr[cf][ks] = *(const bf16x8*)(y1b + ((size_t)(kt*8 + ks*4 + l4)*128 + wave*32 + cf*16 + l15)*8);
    const char* ab = (const char*)&abuf[cur][0];
    bf16x8 afr[2][2];
#pragma unroll
    for (int rf = 0; rf < 2; rf++){
      int row = rf*16 + l15;
      int sw = (row & 7) << 4;
#pragma unroll
      for (int ks = 0; ks < 2; ks++)
        afr[rf][ks] = *(const bf16x8*)(ab + row*128 + ((ks*64 + l4*16) ^ sw));
    }
#pragma unroll
    for (int ks = 0; ks < 2; ks++)
#pragma unroll
      for (int rf = 0; rf < 2; rf++)
#pragma unroll
        for (int cf = 0; cf < 2; cf++)
          MFMA16(acc[rf][cf], afr[rf][ks], bfr[cf][ks]);
    __syncthreads();
  }

#pragma unroll
  for (int rf = 0; rf < 2; rf++)
#pragma unroll
    for (int cf = 0; cf < 2; cf++){
      int col = wave*32 + cf*16 + l15;
#pragma unroll
      for (int r = 0; r < 4; r++){
        int row = rb*32 + rf*16 + l4*4 + r;
        if (row < NVRT){
          float v = fmaxf(y0[((size_t)b*MP + row)*128 + col] + acc[rf][cf][r], 0.f);
          if (EPI == 0) xnext[((size_t)b*MP + row)*160 + 3 + col] = f2bf(v);
          else          outf[((size_t)b*NVRT + row)*128 + col] = v;
        }
      }
    }
}

// ---------------------------------------------------------------- position head: new_pos = pos + tanh(feat @ w_lin1 + b_lin1)
__global__ void k_head(const float* __restrict__ feat, const float* __restrict__ pos,
                       const float* __restrict__ wl1, const float* __restrict__ bl1,
                       float* __restrict__ opos)
{
  int grow = blockIdx.x * 4 + (threadIdx.x >> 6);
  int lane = threadIdx.x & 63;
  int b = grow / NVRT, row = grow - b * NVRT;
  int c0 = lane * 2;
  f32x2 v = *(const f32x2*)(feat + ((size_t)b * NVRT + row) * 128 + c0);
  float p[3];
#pragma unroll
  for (int j = 0; j < 3; j++){
    p[j] = v[0] * wl1[c0*3 + j] + v[1] * wl1[c0*3 + 3 + j];
#pragma unroll
    for (int off = 1; off < 64; off <<= 1)
      p[j] += __shfl_xor(p[j], off);
  }
  if (lane == 0){
    size_t po = ((size_t)b * NVRT + row) * 3;
#pragma unroll
    for (int j = 0; j < 3; j++)
      opos[po + j] = pos[po + j] + tanhf(p[j] + bl1[j]);
  }
}

// ================================================================ host
extern "C" void kernel_launch(void* const* d_in, const int* in_sizes, int n_in,
                              void* d_out, int out_size, void* d_ws, size_t ws_size,
                              hipStream_t stream)
{
  const float* conv[4] = {(const float*)d_in[0], (const float*)d_in[1],
                          (const float*)d_in[2], (const float*)d_in[3]};
  const float* adj   = (const float*)d_in[4];
  const float* pos   = (const float*)d_in[5];
  const float* vfeat = (const float*)d_in[6];
  const float* wlin0 = (const float*)d_in[7];
  const float* blin0 = (const float*)d_in[8];
  const float* gw[6] = {(const float*)d_in[9],  (const float*)d_in[10],
                        (const float*)d_in[11], (const float*)d_in[12],
                        (const float*)d_in[13], (const float*)d_in[14]};
  const float* wlin1 = (const float*)d_in[15];
  const float* blin1 = (const float*)d_in[16];

  char* ws = (char*)d_ws;
  size_t off = 0;
  auto take = [&](size_t bytes)->char* {
    char* p = ws + off;
    off += (bytes + 255) & ~(size_t)255;
    return p;
  };
  unsigned short* ftT  = (unsigned short*)take(FT_TOT * 2);
  unsigned short* G    = (unsigned short*)take(G_TOT * 2);
  unsigned short* adjP = (unsigned short*)take((size_t)NB*NRB2*NKT*4096);
  unsigned short* wl0p = (unsigned short*)take((size_t)3840*128*2);
  unsigned short* w0p0 = (unsigned short*)take((size_t)288*128*2);
  unsigned short* w1p0 = (unsigned short*)take((size_t)288*128*2);
  unsigned short* w0p1 = (unsigned short*)take((size_t)160*128*2);
  unsigned short* w1p1 = (unsigned short*)take((size_t)160*128*2);
  unsigned short* w0p2 = (unsigned short*)take((size_t)160*128*2);
  unsigned short* w1p2 = (unsigned short*)take((size_t)160*128*2);
  unsigned short* vf   = (unsigned short*)take((size_t)NB*MP*288*2);
  unsigned short* x1   = (unsigned short*)take((size_t)NB*MP*160*2);
  unsigned short* x2   = (unsigned short*)take((size_t)NB*MP*160*2);
  float*          y0   = (float*)take((size_t)NB*MP*128*4);
  unsigned short* y1p  = (unsigned short*)take((size_t)NB*MP*128*2);

  float* out_pos  = (float*)d_out;
  float* out_feat = out_pos + (size_t)NB*NVRT*3;

  // 1. transposes (one dispatch)
  k_transpose_all<<<dim3(1536, NB), dim3(32, 8), 0, stream>>>(conv[0], conv[1], conv[2], conv[3], ftT);
  // 2. weight packing (one dispatch)
  PWArgs pw;
  pw.src[0]=wlin0; pw.dst[0]=wl0p; pw.ksrc[0]=3840; pw.nsrc[0]=128;
  pw.src[1]=gw[0]; pw.dst[1]=w0p0; pw.ksrc[1]=259;  pw.nsrc[1]=131;
  pw.src[2]=gw[1]; pw.dst[2]=w1p0; pw.ksrc[2]=259;  pw.nsrc[2]=131;
  pw.src[3]=gw[2]; pw.dst[3]=w0p1; pw.ksrc[3]=131;  pw.nsrc[3]=128;
  pw.src[4]=gw[3]; pw.dst[4]=w1p1; pw.ksrc[4]=131;  pw.nsrc[4]=128;
  pw.src[5]=gw[4]; pw.dst[5]=w0p2; pw.ksrc[5]=131;  pw.nsrc[5]=128;
  pw.src[6]=gw[5]; pw.dst[6]=w1p2; pw.ksrc[6]=131;  pw.nsrc[6]=128;
  k_packw_all<<<2528, 256, 0, stream>>>(pw);
  // 3. pixel projection G = ftT @ w_lin0 (the linearity trick)
  k_gproj<<<1042, 256, 0, stream>>>(ftT, wl0p, G);
  // 4. gather-blend projected from G + vf base + x1/x2 pads
  k_prep2<<<dim3(MP/4, NB), 256, 0, stream>>>(vfeat, pos, G, blin0, vf, x1, x2);
  // 5. pack adjacency to bf16 swizzled tiles
  k_adjpack<<<dim3(NKT, NRB2, NB), 256, 0, stream>>>(adj, adjP);
  // 6-8. three graph convs
  k_xw2<288><<<dim3(NRB2, NB), 256, 0, stream>>>(vf, w0p0, w1p0, y0, y1p);
  k_adj2<0><<<dim3(NRB2, NB), 256, 0, stream>>>(adjP, y1p, y0, x1, nullptr);
  k_xw2<160><<<dim3(NRB2, NB), 256, 0, stream>>>(x1, w0p1, w1p1, y0, y1p);
  k_adj2<0><<<dim3(NRB2, NB), 256, 0, stream>>>(adjP, y1p, y0, x2, nullptr);
  k_xw2<160><<<dim3(NRB2, NB), 256, 0, stream>>>(x2, w0p2, w1p2, y0, y1p);
  k_adj2<1><<<dim3(NRB2, NB), 256, 0, stream>>>(adjP, y1p, y0, nullptr, out_feat);
  // 9. position head
  k_head<<<NB*NVRT/4, 256, 0, stream>>>(out_feat, pos, wlin1, blin1, out_pos);
  (void)in_sizes; (void)n_in; (void)out_size; (void)ws_size;
}

// Round 6
// 291.726 us; speedup vs baseline: 1.7031x; 1.0988x over previous
//
#include <hip/hip_runtime.h>
#include <hip/hip_bf16.h>

typedef __attribute__((ext_vector_type(8))) short bf16x8;
typedef __attribute__((ext_vector_type(4))) float f32x4;
typedef __attribute__((ext_vector_type(2))) float f32x2;
typedef long long i64;

static __device__ __forceinline__ float bf2f(unsigned short u){
  return __uint_as_float(((unsigned)u) << 16);
}
static __device__ __forceinline__ float bflo(unsigned v){ return __uint_as_float(v << 16); }
static __device__ __forceinline__ float bfhi(unsigned v){ return __uint_as_float(v & 0xffff0000u); }
static __device__ __forceinline__ unsigned short f2bf(float f){
  unsigned u = __float_as_uint(f);
  u += 0x7FFFu + ((u >> 16) & 1u);
  return (unsigned short)(u >> 16);
}
// OCP e4m3fn encode, RNE, saturating (no inf; 0x7e = 448 max)
static __device__ __forceinline__ unsigned f2e4m3(float x){
  unsigned b = __float_as_uint(x);
  unsigned s = (b >> 31) << 7;
  b &= 0x7fffffffu;
  if (b >= 0x43e80000u) return s | 0x7eu;                       // >= 464 -> 448
  if (b < 0x3c800000u)                                          // < 2^-6 -> denormal (quantum 2^-9)
    return s | (unsigned)rintf(__uint_as_float(b) * 512.f);
  unsigned b2 = b + 0x7ffffu + ((b >> 20) & 1u);
  return s | (((b2 >> 23) - 120u) << 3) | ((b2 >> 20) & 7u);
}
static __device__ __forceinline__ void gload_lds16(const void* g, void* l){
  __builtin_amdgcn_global_load_lds((const __attribute__((address_space(1))) unsigned int*)g,
                                   (__attribute__((address_space(3))) unsigned int*)l, 16, 0, 0);
}

#define MFMA16(acc, a, b) (acc) = __builtin_amdgcn_mfma_f32_16x16x32_bf16((a),(b),(acc),0,0,0)
#define MFMA8(acc, a, b)  (acc) = __builtin_amdgcn_mfma_f32_16x16x32_fp8_fp8((a),(b),(acc),0,0,0)

#define NB    8
#define NVRT  2562
#define MP    2624     /* rows padded to 82*32 = 164*16 */
#define NRB2  82       /* 32-row blocks (xw2) */
#define NRB16 164      /* 16-row blocks (adj) */
#define NKT8  21       /* K tiles of 128 over 2688 */
#define KOCT  336      /* 2688/8 k-octets in y1p8 */
#define YO    ((size_t)KOCT*128*8)   /* y1p8 per-batch bytes */

// channel-last bf16 feature-map buffer bases (elements)
#define FT_B0 0ul
#define FT_B1 6422528ul
#define FT_B2 9633792ul
#define FT_B3 11239424ul
#define FT_TOT 12042240ul

// pixel-projection buffer bases (elements), layout [B*HW][128] bf16 per map
#define G_B0 0ul
#define G_B1 3211264ul
#define G_B2 4014080ul
#define G_B3 4214784ul
#define G_TOT 4264960ul

// ---------------------------------------------------------------- unified transpose: 4 maps, [B,C,H,W]f32 -> [B,HW,C]bf16
__global__ void k_transpose_all(const float* __restrict__ c0, const float* __restrict__ c1,
                                const float* __restrict__ c2, const float* __restrict__ c3,
                                unsigned short* __restrict__ ftT)
{
  __shared__ float tile[32][33];
  int bx = blockIdx.x, b = blockIdx.y;
  int m, local;
  if (bx < 784)      { m = 0; local = bx; }
  else if (bx < 1184){ m = 1; local = bx - 784; }
  else if (bx < 1408){ m = 2; local = bx - 1184; }
  else               { m = 3; local = bx - 1408; }
  int HW  = (m==0)?3136:(m==1)?784:(m==2)?196:49;
  int C   = 256 << m;
  int nbx = (m==0)?98:(m==1)?25:(m==2)?7:2;
  size_t fb = (m==0)?FT_B0:(m==1)?FT_B1:(m==2)?FT_B2:FT_B3;
  const float* src = (m==0)?c0:(m==1)?c1:(m==2)?c2:c3;

  int hw0 = (local % nbx) * 32, c0i = (local / nbx) * 32;
  int tx = threadIdx.x, ty = threadIdx.y;
  const float* s = src + (size_t)b * C * HW;
#pragma unroll
  for (int i = 0; i < 4; i++){
    int c = c0i + ty + i*8, hw = hw0 + tx;
    tile[ty + i*8][tx] = (c < C && hw < HW) ? s[(size_t)c * HW + hw] : 0.f;
  }
  __syncthreads();
  unsigned short* d = ftT + fb + (size_t)b * HW * C;
#pragma unroll
  for (int i = 0; i < 4; i++){
    int hw = hw0 + ty + i*8, c = c0i + tx;
    if (hw < HW && c < C) d[(size_t)hw * C + c] = f2bf(tile[tx][ty + i*8]);
  }
}

// ---------------------------------------------------------------- unified weight pack: 7 weights -> [Kp/8][128][8] bf16
struct PWArgs {
  const float* src[7];
  unsigned short* dst[7];
  int ksrc[7], nsrc[7];
};
__global__ void k_packw_all(PWArgs a)
{
  const int cb[8] = {0,491520,528384,565248,585728,606208,626688,647168};
  int g = blockIdx.x * 256 + threadIdx.x;
#pragma unroll
  for (int s = 0; s < 7; s++){
    if (g >= cb[s] && g < cb[s+1]){
      int li = g - cb[s];
      int k = li >> 7, c = li & 127;
      int ks = a.ksrc[s], ns = a.nsrc[s];
      float v = (k < ks) ? a.src[s][(size_t)k * ns + c] : 0.f;
      a.dst[s][((size_t)(k >> 3) * 128 + c) * 8 + (k & 7)] = f2bf(v);
    }
  }
}

// ---------------------------------------------------------------- pixel projection: G_m = ftT_m @ W_m  (linearity trick)
__global__ __launch_bounds__(256) void k_gproj(
    const unsigned short* __restrict__ ftT,
    const unsigned short* __restrict__ wp,
    unsigned short* __restrict__ G)
{
  int bx = blockIdx.x;
  int m, tile;
  if (bx < 784)      { m = 0; tile = bx; }
  else if (bx < 980) { m = 1; tile = bx - 784; }
  else if (bx < 1029){ m = 2; tile = bx - 980; }
  else               { m = 3; tile = bx - 1029; }
  int C    = 256 << m;
  int rows = 8 * ((m==0)?3136:(m==1)?784:(m==2)?196:49);
  size_t fb = (m==0)?FT_B0:(m==1)?FT_B1:(m==2)?FT_B2:FT_B3;
  size_t gb = (m==0)?G_B0:(m==1)?G_B1:(m==2)?G_B2:G_B3;
  int ko8 = ((m==0)?0:(m==1)?256:(m==2)?768:1792) >> 3;

  int t = threadIdx.x, wave = t >> 6, lane = t & 63;
  int rf = wave & 1, ch = wave >> 1;
  int l15 = lane & 15, l4 = lane >> 4;
  int row = tile*32 + rf*16 + l15;
  int arow = (row < rows) ? row : 0;
  const unsigned short* xp = ftT + fb + (size_t)arow * C + l4 * 8;

  f32x4 acc[4];
#pragma unroll
  for (int c = 0; c < 4; c++) acc[c] = (f32x4){0,0,0,0};

  for (int kb = 0; kb < C; kb += 32){
    bf16x8 a = *(const bf16x8*)(xp + kb);
    size_t bo = ((size_t)(ko8 + (kb>>3) + l4) * 128 + ch*64 + l15) * 8;
#pragma unroll
    for (int c = 0; c < 4; c++){
      bf16x8 bb = *(const bf16x8*)(wp + bo + c*128);
      MFMA16(acc[c], a, bb);
    }
  }
#pragma unroll
  for (int c = 0; c < 4; c++){
    int col = ch*64 + c*16 + l15;
#pragma unroll
    for (int r = 0; r < 4; r++){
      int orow = tile*32 + rf*16 + l4*4 + r;
      if (orow < rows) G[gb + (size_t)orow*128 + col] = f2bf(acc[c][r]);
    }
  }
}

// ---------------------------------------------------------------- prep: gather-blend projected from G + vf base + x1/x2 pads
__global__ void k_prep2(const float* __restrict__ vfeat, const float* __restrict__ pos,
                        const unsigned short* __restrict__ G,
                        const float* __restrict__ bias,
                        unsigned short* __restrict__ vf,
                        unsigned short* __restrict__ x1,
                        unsigned short* __restrict__ x2)
{
  int b = blockIdx.y;
  int row = blockIdx.x * 4 + (threadIdx.x >> 6);
  int lane = threadIdx.x & 63;
  size_t vfo = ((size_t)b * MP + row) * 288;
  size_t xo  = ((size_t)b * MP + row) * 160;
  if (row < NVRT){
    size_t src = (size_t)b * NVRT + row;
    float px = fminf(fmaxf(pos[src*3 + 0], -1.f), 1.f);
    float py = fminf(fmaxf(pos[src*3 + 1], -1.f), 1.f);
    int c0 = lane * 2;
    float s0 = bias[c0], s1 = bias[c0 + 1];
#pragma unroll
    for (int m = 0; m < 4; m++){
      int W = 56 >> m;
      int HW = W * W;
      size_t gb = (m==0)?G_B0:(m==1)?G_B1:(m==2)?G_B2:G_B3;
      float gx = (px + 1.f) * 0.5f * (float)(W - 1);
      float gy = (py + 1.f) * 0.5f * (float)(W - 1);
      int x0 = (int)floorf(gx), y0 = (int)floorf(gy);
      float wx = gx - (float)x0, wy = gy - (float)y0;
      int x1i = min(x0 + 1, W - 1), y1i = min(y0 + 1, W - 1);
      const unsigned short* g = G + gb + (size_t)b * HW * 128;
      unsigned v00 = *(const unsigned*)(g + ((size_t)(y0 *W + x0 ))*128 + c0);
      unsigned v01 = *(const unsigned*)(g + ((size_t)(y0 *W + x1i))*128 + c0);
      unsigned v10 = *(const unsigned*)(g + ((size_t)(y1i*W + x0 ))*128 + c0);
      unsigned v11 = *(const unsigned*)(g + ((size_t)(y1i*W + x1i))*128 + c0);
      float w00 = (1.f-wx)*(1.f-wy), w01 = wx*(1.f-wy);
      float w10 = (1.f-wx)*wy,       w11 = wx*wy;
      s0 += w00*bflo(v00) + w01*bflo(v01) + w10*bflo(v10) + w11*bflo(v11);
      s1 += w00*bfhi(v00) + w01*bfhi(v01) + w10*bfhi(v10) + w11*bfhi(v11);
    }
    vf[vfo + 131 + c0]     = f2bf(s0);
    vf[vfo + 131 + c0 + 1] = f2bf(s1);
    float2 fv = *(const float2*)(vfeat + src*128 + c0);
    vf[vfo + c0]     = f2bf(fv.x);
    vf[vfo + c0 + 1] = f2bf(fv.y);
    if (lane < 3){
      unsigned short v = f2bf(pos[src*3 + lane]);
      vf[vfo + 128 + lane] = v;
      x1[xo + lane] = v;
      x2[xo + lane] = v;
    }
    if (lane >= 32 && lane < 61) vf[vfo + 259 + (lane - 32)] = 0;
    if (lane < 29){ x1[xo + 131 + lane] = 0; x2[xo + 131 + lane] = 0; }
  } else {
    for (int c = lane; c < 288; c += 64) vf[vfo + c] = 0;
    for (int c = lane; c < 160; c += 64){ x1[xo + c] = 0; x2[xo + c] = 0; }
  }
}

// ---------------------------------------------------------------- pack adjacency f32 -> fp8 e4m3 (x1024) MFMA tiles
// tile (b, rb16, kt128) = 2048 B; byte = 128*row + 8*(koct ^ row) + i  (XOR involution)
__global__ void k_adjpack8(const float* __restrict__ adj, unsigned char* __restrict__ adjP)
{
  int kt = blockIdx.x, rb = blockIdx.y, b = blockIdx.z;
  int t = threadIdx.x;
  int r = t >> 4, kseg = t & 15;
  int grow = rb*16 + r, gk = kt*128 + kseg*8;
  float v[8];
  if (grow < NVRT && gk + 8 <= NVRT){
    const float4* p = (const float4*)(adj + ((size_t)b*NVRT + grow)*NVRT + gk);
    float4 f0 = p[0], f1 = p[1];
    v[0]=f0.x; v[1]=f0.y; v[2]=f0.z; v[3]=f0.w;
    v[4]=f1.x; v[5]=f1.y; v[6]=f1.z; v[7]=f1.w;
  } else if (grow < NVRT){
    const float* ap = adj + ((size_t)b*NVRT + grow)*NVRT;
#pragma unroll
    for (int e = 0; e < 8; e++){ int k = gk + e; v[e] = (k < NVRT) ? ap[k] : 0.f; }
  } else {
#pragma unroll
    for (int e = 0; e < 8; e++) v[e] = 0.f;
  }
  unsigned long long q = 0;
#pragma unroll
  for (int e = 0; e < 8; e++)
    q |= (unsigned long long)f2e4m3(v[e] * 1024.f) << (8*e);
  unsigned char* tb = adjP + (((size_t)b*NRB16 + rb)*NKT8 + kt) * 2048;
  *(unsigned long long*)(tb + 128*r + 8*(kseg ^ r)) = q;
}

// ---------------------------------------------------------------- y0 = x@w0 (f32), y1p8 = fp8(x@w1)
template<int KX>
__global__ __launch_bounds__(256) void k_xw2(
    const unsigned short* __restrict__ x,
    const unsigned short* __restrict__ wp0,
    const unsigned short* __restrict__ wp1,
    float* __restrict__ y0,
    unsigned char* __restrict__ y1p8)
{
  int b = blockIdx.y, rb = blockIdx.x * 32;
  int t = threadIdx.x, wave = t >> 6, lane = t & 63;
  int rf = wave & 1, ch = wave >> 1;
  int l15 = lane & 15, l4 = lane >> 4;
  f32x4 a0[4], a1[4];
#pragma unroll
  for (int c = 0; c < 4; c++){ a0[c] = (f32x4){0,0,0,0}; a1[c] = (f32x4){0,0,0,0}; }
  int row = rb + rf*16 + l15;
  const unsigned short* xp = x + ((size_t)b * MP + row) * KX + l4 * 8;
#pragma unroll
  for (int kb = 0; kb < KX; kb += 32){
    bf16x8 a = *(const bf16x8*)(xp + kb);
    size_t bo = ((size_t)((kb>>3) + l4) * 128 + ch*64 + l15) * 8;
#pragma unroll
    for (int c = 0; c < 4; c++){
      bf16x8 b0 = *(const bf16x8*)(wp0 + bo + c*128);
      MFMA16(a0[c], a, b0);
      bf16x8 b1 = *(const bf16x8*)(wp1 + bo + c*128);
      MFMA16(a1[c], a, b1);
    }
  }
  unsigned char* yb = y1p8 + (size_t)b * YO;
#pragma unroll
  for (int c = 0; c < 4; c++){
    int col = ch*64 + c*16 + l15;
    int orow0 = rb + rf*16 + l4*4;
#pragma unroll
    for (int r = 0; r < 4; r++)
      y0[((size_t)b * MP + orow0 + r) * 128 + col] = a0[c][r];
    unsigned q = f2e4m3(a1[c][0]) | (f2e4m3(a1[c][1]) << 8)
               | (f2e4m3(a1[c][2]) << 16) | (f2e4m3(a1[c][3]) << 24);
    *(unsigned*)(yb + ((size_t)(orow0 >> 3) * 128 + col) * 8 + (orow0 & 7)) = q;
  }
}

// ---------------------------------------------------------------- h = relu(y0 + adj@y1/1024) from fp8 tiles
// 16-row blocks, grid (164, 8); EPI=1 additionally fuses the lin1 position head
template<int EPI>
__global__ __launch_bounds__(256) void k_adj8(
    const unsigned char* __restrict__ adjP,
    const unsigned char* __restrict__ y1p8,
    const float* __restrict__ y0,
    unsigned short* __restrict__ xnext,
    float* __restrict__ outf,
    const float* __restrict__ pos,
    const float* __restrict__ wl1, const float* __restrict__ bl1,
    float* __restrict__ opos)
{
  __shared__ __align__(16) unsigned char abuf[2][2048];
  __shared__ float hbuf[16][128];
  int rb = blockIdx.x, b = blockIdx.y;
  int t = threadIdx.x, w = t >> 6, lane = t & 63;
  int l15 = lane & 15, l4 = lane >> 4;
  const unsigned char* tb = adjP + (((size_t)b*NRB16 + rb)*NKT8) * 2048;
  const unsigned char* yb = y1p8 + (size_t)b * YO;

  f32x4 acc[2];
  acc[0] = (f32x4){0,0,0,0};
  acc[1] = (f32x4){0,0,0,0};

  auto stage = [&](int kt, int bufi){
    if (w < 2)
      gload_lds16(tb + (size_t)kt*2048 + w*1024 + lane*16, &abuf[bufi][w*1024]);
  };

  stage(0, 0);
  __syncthreads();

  for (int kt = 0; kt < NKT8; ++kt){
    int cur = kt & 1;
    if (kt < NKT8-1) stage(kt+1, cur ^ 1);
    const unsigned char* ab = &abuf[cur][0];
#pragma unroll
    for (int sel = 0; sel < 2; sel++){
#pragma unroll
      for (int ks = 0; ks < 2; ks++){
        int koct = sel*8 + ks*4 + l4;
        i64 a = *(const i64*)(ab + 128*l15 + 8*(koct ^ l15));
        const unsigned char* bp = yb + ((size_t)(kt*16 + koct)*128 + w*32 + l15)*8;
        i64 b0 = *(const i64*)(bp);
        i64 b1 = *(const i64*)(bp + 128);
        MFMA8(acc[0], a, b0);
        MFMA8(acc[1], a, b1);
      }
    }
    __syncthreads();
  }

#pragma unroll
  for (int cf = 0; cf < 2; cf++){
    int col = w*32 + cf*16 + l15;
#pragma unroll
    for (int r = 0; r < 4; r++){
      int row16 = l4*4 + r;
      int row = rb*16 + row16;
      float v = 0.f;
      if (row < NVRT)
        v = fmaxf(y0[((size_t)b*MP + row)*128 + col] + acc[cf][r] * 0.0009765625f, 0.f);
      if (EPI == 0){
        if (row < NVRT) xnext[((size_t)b*MP + row)*160 + 3 + col] = f2bf(v);
      } else {
        if (row < NVRT) outf[((size_t)b*NVRT + row)*128 + col] = v;
        hbuf[row16][col] = v;
      }
    }
  }

  if (EPI == 1){
    __syncthreads();
#pragma unroll
    for (int rr = 0; rr < 4; rr++){
      int row16 = w*4 + rr;
      int grow = rb*16 + row16;
      if (grow < NVRT){
        int c0 = lane * 2;
        float v0 = hbuf[row16][c0], v1 = hbuf[row16][c0+1];
        float p[3];
#pragma unroll
        for (int j = 0; j < 3; j++){
          p[j] = v0 * wl1[c0*3 + j] + v1 * wl1[c0*3 + 3 + j];
#pragma unroll
          for (int off = 1; off < 64; off <<= 1)
            p[j] += __shfl_xor(p[j], off);
        }
        if (lane == 0){
          size_t po = ((size_t)b * NVRT + grow) * 3;
#pragma unroll
          for (int j = 0; j < 3; j++)
            opos[po + j] = pos[po + j] + tanhf(p[j] + bl1[j]);
        }
      }
    }
  }
}

// ================================================================ host
extern "C" void kernel_launch(void* const* d_in, const int* in_sizes, int n_in,
                              void* d_out, int out_size, void* d_ws, size_t ws_size,
                              hipStream_t stream)
{
  const float* conv[4] = {(const float*)d_in[0], (const float*)d_in[1],
                          (const float*)d_in[2], (const float*)d_in[3]};
  const float* adj   = (const float*)d_in[4];
  const float* pos   = (const float*)d_in[5];
  const float* vfeat = (const float*)d_in[6];
  const float* wlin0 = (const float*)d_in[7];
  const float* blin0 = (const float*)d_in[8];
  const float* gw[6] = {(const float*)d_in[9],  (const float*)d_in[10],
                        (const float*)d_in[11], (const float*)d_in[12],
                        (const float*)d_in[13], (const float*)d_in[14]};
  const float* wlin1 = (const float*)d_in[15];
  const float* blin1 = (const float*)d_in[16];

  char* ws = (char*)d_ws;
  size_t off = 0;
  auto take = [&](size_t bytes)->char* {
    char* p = ws + off;
    off += (bytes + 255) & ~(size_t)255;
    return p;
  };
  unsigned short* ftT  = (unsigned short*)take(FT_TOT * 2);
  unsigned short* G    = (unsigned short*)take(G_TOT * 2);
  unsigned char*  adjP = (unsigned char*)take((size_t)NB*NRB16*NKT8*2048);
  unsigned short* wl0p = (unsigned short*)take((size_t)3840*128*2);
  unsigned short* w0p0 = (unsigned short*)take((size_t)288*128*2);
  unsigned short* w1p0 = (unsigned short*)take((size_t)288*128*2);
  unsigned short* w0p1 = (unsigned short*)take((size_t)160*128*2);
  unsigned short* w1p1 = (unsigned short*)take((size_t)160*128*2);
  unsigned short* w0p2 = (unsigned short*)take((size_t)160*128*2);
  unsigned short* w1p2 = (unsigned short*)take((size_t)160*128*2);
  unsigned short* vf   = (unsigned short*)take((size_t)NB*MP*288*2);
  unsigned short* x1   = (unsigned short*)take((size_t)NB*MP*160*2);
  unsigned short* x2   = (unsigned short*)take((size_t)NB*MP*160*2);
  float*          y0   = (float*)take((size_t)NB*MP*128*4);
  unsigned char*  y1p8 = (unsigned char*)take((size_t)NB*YO);

  float* out_pos  = (float*)d_out;
  float* out_feat = out_pos + (size_t)NB*NVRT*3;

  // 0. zero y1p8 (pad octets must be valid fp8, never NaN)
  hipMemsetAsync(y1p8, 0, (size_t)NB*YO, stream);
  // 1. transposes
  k_transpose_all<<<dim3(1536, NB), dim3(32, 8), 0, stream>>>(conv[0], conv[1], conv[2], conv[3], ftT);
  // 2. weight packing
  PWArgs pw;
  pw.src[0]=wlin0; pw.dst[0]=wl0p; pw.ksrc[0]=3840; pw.nsrc[0]=128;
  pw.src[1]=gw[0]; pw.dst[1]=w0p0; pw.ksrc[1]=259;  pw.nsrc[1]=131;
  pw.src[2]=gw[1]; pw.dst[2]=w1p0; pw.ksrc[2]=259;  pw.nsrc[2]=131;
  pw.src[3]=gw[2]; pw.dst[3]=w0p1; pw.ksrc[3]=131;  pw.nsrc[3]=128;
  pw.src[4]=gw[3]; pw.dst[4]=w1p1; pw.ksrc[4]=131;  pw.nsrc[4]=128;
  pw.src[5]=gw[4]; pw.dst[5]=w0p2; pw.ksrc[5]=131;  pw.nsrc[5]=128;
  pw.src[6]=gw[5]; pw.dst[6]=w1p2; pw.ksrc[6]=131;  pw.nsrc[6]=128;
  k_packw_all<<<2528, 256, 0, stream>>>(pw);
  // 3. pixel projection G = ftT @ w_lin0
  k_gproj<<<1042, 256, 0, stream>>>(ftT, wl0p, G);
  // 4. gather-blend + vf base + pads
  k_prep2<<<dim3(MP/4, NB), 256, 0, stream>>>(vfeat, pos, G, blin0, vf, x1, x2);
  // 5. pack adjacency to fp8 swizzled tiles (x1024)
  k_adjpack8<<<dim3(NKT8, NRB16, NB), 256, 0, stream>>>(adj, adjP);
  // 6-8. three graph convs
  k_xw2<288><<<dim3(NRB2, NB), 256, 0, stream>>>(vf, w0p0, w1p0, y0, y1p8);
  k_adj8<0><<<dim3(NRB16, NB), 256, 0, stream>>>(adjP, y1p8, y0, x1, nullptr, nullptr, nullptr, nullptr, nullptr);
  k_xw2<160><<<dim3(NRB2, NB), 256, 0, stream>>>(x1, w0p1, w1p1, y0, y1p8);
  k_adj8<0><<<dim3(NRB16, NB), 256, 0, stream>>>(adjP, y1p8, y0, x2, nullptr, nullptr, nullptr, nullptr, nullptr);
  k_xw2<160><<<dim3(NRB2, NB), 256, 0, stream>>>(x2, w0p2, w1p2, y0, y1p8);
  // 9. final adj GEMM + out_feat + fused position head
  k_adj8<1><<<dim3(NRB16, NB), 256, 0, stream>>>(adjP, y1p8, y0, nullptr, out_feat, pos, wlin1, blin1, out_pos);
  (void)in_sizes; (void)n_in; (void)out_size; (void)ws_size;
}

// Round 7
// 270.564 us; speedup vs baseline: 1.8363x; 1.0782x over previous
//
#include <hip/hip_runtime.h>
#include <hip/hip_bf16.h>

typedef __attribute__((ext_vector_type(8))) short bf16x8;
typedef __attribute__((ext_vector_type(4))) float f32x4;
typedef __attribute__((ext_vector_type(2))) float f32x2;
typedef long long i64;

static __device__ __forceinline__ float bflo(unsigned v){ return __uint_as_float(v << 16); }
static __device__ __forceinline__ float bfhi(unsigned v){ return __uint_as_float(v & 0xffff0000u); }
static __device__ __forceinline__ unsigned short f2bf(float f){
  unsigned u = __float_as_uint(f);
  u += 0x7FFFu + ((u >> 16) & 1u);
  return (unsigned short)(u >> 16);
}
// OCP e4m3fn encode, RNE, saturating
static __device__ __forceinline__ unsigned f2e4m3(float x){
  unsigned b = __float_as_uint(x);
  unsigned s = (b >> 31) << 7;
  b &= 0x7fffffffu;
  if (b >= 0x43e80000u) return s | 0x7eu;
  if (b < 0x3c800000u)
    return s | (unsigned)rintf(__uint_as_float(b) * 512.f);
  unsigned b2 = b + 0x7ffffu + ((b >> 20) & 1u);
  return s | (((b2 >> 23) - 120u) << 3) | ((b2 >> 20) & 7u);
}
static __device__ __forceinline__ void gload_lds16(const void* g, void* l){
  __builtin_amdgcn_global_load_lds((const __attribute__((address_space(1))) unsigned int*)g,
                                   (__attribute__((address_space(3))) unsigned int*)l, 16, 0, 0);
}

#define MFMA16(acc, a, b) (acc) = __builtin_amdgcn_mfma_f32_16x16x32_bf16((a),(b),(acc),0,0,0)
#define MFMA8(acc, a, b)  (acc) = __builtin_amdgcn_mfma_f32_16x16x32_fp8_fp8((a),(b),(acc),0,0,0)

#define NB    8
#define NVRT  2562
#define MP    2624     /* rows padded to 82*32 = 164*16 */
#define NRB2  82       /* 32-row blocks (y1) */
#define NRB16 164      /* 16-row blocks (adj) */
#define NKT8  21       /* K tiles of 128 over 2688 */
#define KOCT  336
#define YO    ((size_t)KOCT*128*8)   /* y1p8 per-batch bytes */

// pixel-projection buffer bases (elements), layout [B*HW][128] bf16 per map
#define G_B0 0ul
#define G_B1 3211264ul
#define G_B2 4014080ul
#define G_B3 4214784ul
#define G_TOT 4264960ul

// ---------------------------------------------------------------- unified weight pack: 7 weights -> [Kp/8][128][8] bf16
struct PWArgs {
  const float* src[7];
  unsigned short* dst[7];
  int ksrc[7], nsrc[7];
};
__global__ void k_packw_all(PWArgs a)
{
  const int cb[8] = {0,491520,528384,565248,585728,606208,626688,647168};
  int g = blockIdx.x * 256 + threadIdx.x;
#pragma unroll
  for (int s = 0; s < 7; s++){
    if (g >= cb[s] && g < cb[s+1]){
      int li = g - cb[s];
      int k = li >> 7, c = li & 127;
      int ks = a.ksrc[s], ns = a.nsrc[s];
      float v = (k < ks) ? a.src[s][(size_t)k * ns + c] : 0.f;
      a.dst[s][((size_t)(k >> 3) * 128 + c) * 8 + (k & 7)] = f2bf(v);
    }
  }
}

// ---------------------------------------------------------------- fused conv-read + pixel projection: G_m = ftT_m @ W_m
// direct from [B,C,HW] f32; per-wave K-split (C/4), strided A gathers, LDS reduce
__global__ __launch_bounds__(256) void k_gproj2(
    const float* __restrict__ c0m, const float* __restrict__ c1m,
    const float* __restrict__ c2m, const float* __restrict__ c3m,
    const unsigned short* __restrict__ wp,
    unsigned short* __restrict__ G)
{
  __shared__ f32x4 red[3][1024];
  int bx = blockIdx.x;
  int m, b, tile;
  if (bx < 784)      { m = 0; b = bx / 98;  tile = bx - b*98; }
  else if (bx < 984) { int l = bx-784;  m = 1; b = l / 25; tile = l - b*25; }
  else if (bx < 1040){ int l = bx-984;  m = 2; b = l / 7;  tile = l - b*7; }
  else               { int l = bx-1040; m = 3; b = l >> 1; tile = l & 1; }
  int C  = 256 << m;
  int HW = (m==0)?3136:(m==1)?784:(m==2)?196:49;
  const float* src = ((m==0)?c0m:(m==1)?c1m:(m==2)?c2m:c3m) + (size_t)b * C * HW;
  size_t gb = ((m==0)?G_B0:(m==1)?G_B1:(m==2)?G_B2:G_B3) + (size_t)b * HW * 128;
  int ko8 = (m==0)?0:(m==1)?32:(m==2)?96:224;

  int t = threadIdx.x, w = t >> 6, lane = t & 63;
  int l15 = lane & 15, l4 = lane >> 4;
  int hw0 = tile * 32;
  int ar0 = min(hw0 + l15, HW - 1);
  int ar1 = min(hw0 + 16 + l15, HW - 1);

  f32x4 acc[2][8];
#pragma unroll
  for (int i = 0; i < 2; i++)
#pragma unroll
    for (int j = 0; j < 8; j++) acc[i][j] = (f32x4){0,0,0,0};

  int kq = C >> 2;
  int kbeg = w * kq, klim = kbeg + kq;
  for (int kb = kbeg; kb < klim; kb += 32){
    bf16x8 a0, a1;
#pragma unroll
    for (int j = 0; j < 8; j++){
      int cc = kb + l4*8 + j;
      a0[j] = (short)f2bf(src[(size_t)cc * HW + ar0]);
      a1[j] = (short)f2bf(src[(size_t)cc * HW + ar1]);
    }
    size_t bo = ((size_t)(ko8 + (kb>>3) + l4) * 128 + l15) * 8;
#pragma unroll
    for (int cf = 0; cf < 8; cf++){
      bf16x8 bb = *(const bf16x8*)(wp + bo + cf*128);
      MFMA16(acc[0][cf], a0, bb);
      MFMA16(acc[1][cf], a1, bb);
    }
  }

  if (w){
#pragma unroll
    for (int rf = 0; rf < 2; rf++)
#pragma unroll
      for (int cf = 0; cf < 8; cf++)
        red[w-1][(rf*8+cf)*64 + lane] = acc[rf][cf];
  }
  __syncthreads();
  if (!w){
#pragma unroll
    for (int rf = 0; rf < 2; rf++)
#pragma unroll
      for (int cf = 0; cf < 8; cf++){
        int i = (rf*8+cf)*64 + lane;
        f32x4 s = acc[rf][cf] + red[0][i] + red[1][i] + red[2][i];
        int col = cf*16 + l15;
#pragma unroll
        for (int r = 0; r < 4; r++){
          int hw = hw0 + rf*16 + l4*4 + r;
          if (hw < HW) G[gb + (size_t)hw*128 + col] = f2bf(s[r]);
        }
      }
  }
}

// ---------------------------------------------------------------- prep: gather-blend from G + vf base + x1/x2 pads + y1p8 tail-zero
__global__ void k_prep2(const float* __restrict__ vfeat, const float* __restrict__ pos,
                        const unsigned short* __restrict__ G,
                        const float* __restrict__ bias,
                        unsigned short* __restrict__ vf,
                        unsigned short* __restrict__ x1,
                        unsigned short* __restrict__ x2,
                        unsigned char* __restrict__ y1p8)
{
  int b = blockIdx.y;
  if (blockIdx.x == 0){
    // zero y1p8 pad octets 328..335 (8 KB) so stale bytes can never be fp8-NaN
    unsigned long long* z = (unsigned long long*)(y1p8 + (size_t)b*YO + (size_t)328*128*8);
    int i = threadIdx.x;
    z[i*4+0] = 0; z[i*4+1] = 0; z[i*4+2] = 0; z[i*4+3] = 0;
  }
  int row = blockIdx.x * 4 + (threadIdx.x >> 6);
  int lane = threadIdx.x & 63;
  size_t vfo = ((size_t)b * MP + row) * 288;
  size_t xo  = ((size_t)b * MP + row) * 160;
  if (row < NVRT){
    size_t src = (size_t)b * NVRT + row;
    float px = fminf(fmaxf(pos[src*3 + 0], -1.f), 1.f);
    float py = fminf(fmaxf(pos[src*3 + 1], -1.f), 1.f);
    int c0 = lane * 2;
    float s0 = bias[c0], s1 = bias[c0 + 1];
#pragma unroll
    for (int m = 0; m < 4; m++){
      int W = 56 >> m;
      int HW = W * W;
      size_t gb = (m==0)?G_B0:(m==1)?G_B1:(m==2)?G_B2:G_B3;
      float gx = (px + 1.f) * 0.5f * (float)(W - 1);
      float gy = (py + 1.f) * 0.5f * (float)(W - 1);
      int x0 = (int)floorf(gx), y0 = (int)floorf(gy);
      float wx = gx - (float)x0, wy = gy - (float)y0;
      int x1i = min(x0 + 1, W - 1), y1i = min(y0 + 1, W - 1);
      const unsigned short* g = G + gb + (size_t)b * HW * 128;
      unsigned v00 = *(const unsigned*)(g + ((size_t)(y0 *W + x0 ))*128 + c0);
      unsigned v01 = *(const unsigned*)(g + ((size_t)(y0 *W + x1i))*128 + c0);
      unsigned v10 = *(const unsigned*)(g + ((size_t)(y1i*W + x0 ))*128 + c0);
      unsigned v11 = *(const unsigned*)(g + ((size_t)(y1i*W + x1i))*128 + c0);
      float w00 = (1.f-wx)*(1.f-wy), w01 = wx*(1.f-wy);
      float w10 = (1.f-wx)*wy,       w11 = wx*wy;
      s0 += w00*bflo(v00) + w01*bflo(v01) + w10*bflo(v10) + w11*bflo(v11);
      s1 += w00*bfhi(v00) + w01*bfhi(v01) + w10*bfhi(v10) + w11*bfhi(v11);
    }
    vf[vfo + 131 + c0]     = f2bf(s0);
    vf[vfo + 131 + c0 + 1] = f2bf(s1);
    float2 fv = *(const float2*)(vfeat + src*128 + c0);
    vf[vfo + c0]     = f2bf(fv.x);
    vf[vfo + c0 + 1] = f2bf(fv.y);
    if (lane < 3){
      unsigned short v = f2bf(pos[src*3 + lane]);
      vf[vfo + 128 + lane] = v;
      x1[xo + lane] = v;
      x2[xo + lane] = v;
    }
    if (lane >= 32 && lane < 61) vf[vfo + 259 + (lane - 32)] = 0;
    if (lane < 29){ x1[xo + 131 + lane] = 0; x2[xo + 131 + lane] = 0; }
  } else {
    for (int c = lane; c < 288; c += 64) vf[vfo + c] = 0;
    for (int c = lane; c < 160; c += 64){ x1[xo + c] = 0; x2[xo + c] = 0; }
  }
}

// ---------------------------------------------------------------- pack adjacency f32 -> fp8 e4m3 (x1024) MFMA tiles
// tile (b, rb16, kt128) = 2048 B; byte = 128*row + 8*(koct ^ row) + i
__global__ void k_adjpack8(const float* __restrict__ adj, unsigned char* __restrict__ adjP)
{
  int kt = blockIdx.x, rb = blockIdx.y, b = blockIdx.z;
  int t = threadIdx.x;
  int r = t >> 4, kseg = t & 15;
  int grow = rb*16 + r, gk = kt*128 + kseg*8;
  float v[8];
  if (grow < NVRT && gk + 8 <= NVRT){
    const float4* p = (const float4*)(adj + ((size_t)b*NVRT + grow)*NVRT + gk);
    float4 f0 = p[0], f1 = p[1];
    v[0]=f0.x; v[1]=f0.y; v[2]=f0.z; v[3]=f0.w;
    v[4]=f1.x; v[5]=f1.y; v[6]=f1.z; v[7]=f1.w;
  } else if (grow < NVRT){
    const float* ap = adj + ((size_t)b*NVRT + grow)*NVRT;
#pragma unroll
    for (int e = 0; e < 8; e++){ int k = gk + e; v[e] = (k < NVRT) ? ap[k] : 0.f; }
  } else {
#pragma unroll
    for (int e = 0; e < 8; e++) v[e] = 0.f;
  }
  unsigned long long q = 0;
#pragma unroll
  for (int e = 0; e < 8; e++)
    q |= (unsigned long long)f2e4m3(v[e] * 1024.f) << (8*e);
  unsigned char* tb = adjP + (((size_t)b*NRB16 + rb)*NKT8 + kt) * 2048;
  *(unsigned long long*)(tb + 128*r + 8*(kseg ^ r)) = q;
}

// ---------------------------------------------------------------- y1p8 = fp8(x @ w1)
template<int KX>
__global__ __launch_bounds__(256) void k_y1(
    const unsigned short* __restrict__ x,
    const unsigned short* __restrict__ wp1,
    unsigned char* __restrict__ y1p8)
{
  int b = blockIdx.y, rb = blockIdx.x * 32;
  int t = threadIdx.x, wave = t >> 6, lane = t & 63;
  int rf = wave & 1, ch = wave >> 1;
  int l15 = lane & 15, l4 = lane >> 4;
  f32x4 a1[4];
#pragma unroll
  for (int c = 0; c < 4; c++) a1[c] = (f32x4){0,0,0,0};
  int row = rb + rf*16 + l15;
  const unsigned short* xp = x + ((size_t)b * MP + row) * KX + l4 * 8;
#pragma unroll
  for (int kb = 0; kb < KX; kb += 32){
    bf16x8 a = *(const bf16x8*)(xp + kb);
    size_t bo = ((size_t)((kb>>3) + l4) * 128 + ch*64 + l15) * 8;
#pragma unroll
    for (int c = 0; c < 4; c++){
      bf16x8 b1 = *(const bf16x8*)(wp1 + bo + c*128);
      MFMA16(a1[c], a, b1);
    }
  }
  unsigned char* yb = y1p8 + (size_t)b * YO;
#pragma unroll
  for (int c = 0; c < 4; c++){
    int col = ch*64 + c*16 + l15;
    int orow0 = rb + rf*16 + l4*4;
    unsigned q = f2e4m3(a1[c][0]) | (f2e4m3(a1[c][1]) << 8)
               | (f2e4m3(a1[c][2]) << 16) | (f2e4m3(a1[c][3]) << 24);
    *(unsigned*)(yb + ((size_t)(orow0 >> 3) * 128 + col) * 8 + (orow0 & 7)) = q;
  }
}

// ---------------------------------------------------------------- h = relu(x@w0 + adj@y1/1024); fused w0 GEMM + fp8 adj GEMM
// EPI=1 additionally fuses the lin1 position head
template<int EPI, int KX>
__global__ __launch_bounds__(256) void k_adj8(
    const unsigned char* __restrict__ adjP,
    const unsigned char* __restrict__ y1p8,
    const unsigned short* __restrict__ x,
    const unsigned short* __restrict__ wp0,
    unsigned short* __restrict__ xnext,
    float* __restrict__ outf,
    const float* __restrict__ pos,
    const float* __restrict__ wl1, const float* __restrict__ bl1,
    float* __restrict__ opos)
{
  __shared__ __align__(16) unsigned char abuf[2][2048];
  __shared__ float hbuf[16][128];
  int rb = blockIdx.x, b = blockIdx.y;
  int t = threadIdx.x, w = t >> 6, lane = t & 63;
  int l15 = lane & 15, l4 = lane >> 4;
  const unsigned char* tb = adjP + (((size_t)b*NRB16 + rb)*NKT8) * 2048;
  const unsigned char* yb = y1p8 + (size_t)b * YO;

  f32x4 acc[2], accW[2];
  acc[0] = (f32x4){0,0,0,0};  acc[1] = (f32x4){0,0,0,0};
  accW[0] = (f32x4){0,0,0,0}; accW[1] = (f32x4){0,0,0,0};

  auto stage = [&](int kt, int bufi){
    if (w < 2)
      gload_lds16(tb + (size_t)kt*2048 + w*1024 + lane*16, &abuf[bufi][w*1024]);
  };

  stage(0, 0);

  // fused x @ w0 (register-only; hides stage(0) latency)
  const unsigned short* xr = x + ((size_t)b*MP + rb*16 + l15)*KX + l4*8;
#pragma unroll
  for (int kb = 0; kb < KX; kb += 32){
    bf16x8 ax = *(const bf16x8*)(xr + kb);
    size_t bo = ((size_t)((kb>>3) + l4)*128 + w*32 + l15)*8;
    MFMA16(accW[0], ax, *(const bf16x8*)(wp0 + bo));
    MFMA16(accW[1], ax, *(const bf16x8*)(wp0 + bo + 128));
  }

  __syncthreads();

  for (int kt = 0; kt < NKT8; ++kt){
    int cur = kt & 1;
    if (kt < NKT8-1) stage(kt+1, cur ^ 1);
    const unsigned char* ab = &abuf[cur][0];
#pragma unroll
    for (int sel = 0; sel < 2; sel++){
#pragma unroll
      for (int ks = 0; ks < 2; ks++){
        int koct = sel*8 + ks*4 + l4;
        i64 a = *(const i64*)(ab + 128*l15 + 8*(koct ^ l15));
        const unsigned char* bp = yb + ((size_t)(kt*16 + koct)*128 + w*32 + l15)*8;
        i64 b0 = *(const i64*)(bp);
        i64 b1 = *(const i64*)(bp + 128);
        MFMA8(acc[0], a, b0);
        MFMA8(acc[1], a, b1);
      }
    }
    __syncthreads();
  }

#pragma unroll
  for (int cf = 0; cf < 2; cf++){
    int col = w*32 + cf*16 + l15;
#pragma unroll
    for (int r = 0; r < 4; r++){
      int row16 = l4*4 + r;
      int row = rb*16 + row16;
      float v = fmaxf(accW[cf][r] + acc[cf][r] * 0.0009765625f, 0.f);
      if (EPI == 0){
        if (row < NVRT) xnext[((size_t)b*MP + row)*160 + 3 + col] = f2bf(v);
      } else {
        if (row < NVRT) outf[((size_t)b*NVRT + row)*128 + col] = v;
        hbuf[row16][col] = v;
      }
    }
  }

  if (EPI == 1){
    __syncthreads();
#pragma unroll
    for (int rr = 0; rr < 4; rr++){
      int row16 = w*4 + rr;
      int grow = rb*16 + row16;
      if (grow < NVRT){
        int c0 = lane * 2;
        float v0 = hbuf[row16][c0], v1 = hbuf[row16][c0+1];
        float p[3];
#pragma unroll
        for (int j = 0; j < 3; j++){
          p[j] = v0 * wl1[c0*3 + j] + v1 * wl1[c0*3 + 3 + j];
#pragma unroll
          for (int off = 1; off < 64; off <<= 1)
            p[j] += __shfl_xor(p[j], off);
        }
        if (lane == 0){
          size_t po = ((size_t)b * NVRT + grow) * 3;
#pragma unroll
          for (int j = 0; j < 3; j++)
            opos[po + j] = pos[po + j] + tanhf(p[j] + bl1[j]);
        }
      }
    }
  }
}

// ================================================================ host
extern "C" void kernel_launch(void* const* d_in, const int* in_sizes, int n_in,
                              void* d_out, int out_size, void* d_ws, size_t ws_size,
                              hipStream_t stream)
{
  const float* conv[4] = {(const float*)d_in[0], (const float*)d_in[1],
                          (const float*)d_in[2], (const float*)d_in[3]};
  const float* adj   = (const float*)d_in[4];
  const float* pos   = (const float*)d_in[5];
  const float* vfeat = (const float*)d_in[6];
  const float* wlin0 = (const float*)d_in[7];
  const float* blin0 = (const float*)d_in[8];
  const float* gw[6] = {(const float*)d_in[9],  (const float*)d_in[10],
                        (const float*)d_in[11], (const float*)d_in[12],
                        (const float*)d_in[13], (const float*)d_in[14]};
  const float* wlin1 = (const float*)d_in[15];
  const float* blin1 = (const float*)d_in[16];

  char* ws = (char*)d_ws;
  size_t off = 0;
  auto take = [&](size_t bytes)->char* {
    char* p = ws + off;
    off += (bytes + 255) & ~(size_t)255;
    return p;
  };
  unsigned short* G    = (unsigned short*)take(G_TOT * 2);
  unsigned char*  adjP = (unsigned char*)take((size_t)NB*NRB16*NKT8*2048);
  unsigned short* wl0p = (unsigned short*)take((size_t)3840*128*2);
  unsigned short* w0p0 = (unsigned short*)take((size_t)288*128*2);
  unsigned short* w1p0 = (unsigned short*)take((size_t)288*128*2);
  unsigned short* w0p1 = (unsigned short*)take((size_t)160*128*2);
  unsigned short* w1p1 = (unsigned short*)take((size_t)160*128*2);
  unsigned short* w0p2 = (unsigned short*)take((size_t)160*128*2);
  unsigned short* w1p2 = (unsigned short*)take((size_t)160*128*2);
  unsigned short* vf   = (unsigned short*)take((size_t)NB*MP*288*2);
  unsigned short* x1   = (unsigned short*)take((size_t)NB*MP*160*2);
  unsigned short* x2   = (unsigned short*)take((size_t)NB*MP*160*2);
  unsigned char*  y1p8 = (unsigned char*)take((size_t)NB*YO);

  float* out_pos  = (float*)d_out;
  float* out_feat = out_pos + (size_t)NB*NVRT*3;

  // 1. weight packing
  PWArgs pw;
  pw.src[0]=wlin0; pw.dst[0]=wl0p; pw.ksrc[0]=3840; pw.nsrc[0]=128;
  pw.src[1]=gw[0]; pw.dst[1]=w0p0; pw.ksrc[1]=259;  pw.nsrc[1]=131;
  pw.src[2]=gw[1]; pw.dst[2]=w1p0; pw.ksrc[2]=259;  pw.nsrc[2]=131;
  pw.src[3]=gw[2]; pw.dst[3]=w0p1; pw.ksrc[3]=131;  pw.nsrc[3]=128;
  pw.src[4]=gw[3]; pw.dst[4]=w1p1; pw.ksrc[4]=131;  pw.nsrc[4]=128;
  pw.src[5]=gw[4]; pw.dst[5]=w0p2; pw.ksrc[5]=131;  pw.nsrc[5]=128;
  pw.src[6]=gw[5]; pw.dst[6]=w1p2; pw.ksrc[6]=131;  pw.nsrc[6]=128;
  k_packw_all<<<2528, 256, 0, stream>>>(pw);
  // 2. fused conv transpose + pixel projection G = ft^T @ w_lin0
  k_gproj2<<<1056, 256, 0, stream>>>(conv[0], conv[1], conv[2], conv[3], wl0p, G);
  // 3. gather-blend + vf base + pads + y1p8 tail-zero
  k_prep2<<<dim3(MP/4, NB), 256, 0, stream>>>(vfeat, pos, G, blin0, vf, x1, x2, y1p8);
  // 4. pack adjacency to fp8 swizzled tiles (x1024)
  k_adjpack8<<<dim3(NKT8, NRB16, NB), 256, 0, stream>>>(adj, adjP);
  // 5-10. three graph convs (y1 GEMM + fused w0/adj GEMM)
  k_y1<288><<<dim3(NRB2, NB), 256, 0, stream>>>(vf, w1p0, y1p8);
  k_adj8<0,288><<<dim3(NRB16, NB), 256, 0, stream>>>(adjP, y1p8, vf, w0p0, x1, nullptr, nullptr, nullptr, nullptr, nullptr);
  k_y1<160><<<dim3(NRB2, NB), 256, 0, stream>>>(x1, w1p1, y1p8);
  k_adj8<0,160><<<dim3(NRB16, NB), 256, 0, stream>>>(adjP, y1p8, x1, w0p1, x2, nullptr, nullptr, nullptr, nullptr, nullptr);
  k_y1<160><<<dim3(NRB2, NB), 256, 0, stream>>>(x2, w1p2, y1p8);
  k_adj8<1,160><<<dim3(NRB16, NB), 256, 0, stream>>>(adjP, y1p8, x2, w0p2, nullptr, out_feat, pos, wlin1, blin1, out_pos);
  (void)in_sizes; (void)n_in; (void)out_size; (void)ws_size;
}